// Round 4
// baseline (860.502 us; speedup 1.0000x reference)
//
#include <hip/hip_runtime.h>
#include <hip/hip_bf16.h>
#include <cstdint>
#include <cstddef>

typedef __hip_bfloat16 bf16;

__device__ __forceinline__ float bflo(unsigned u) { return __uint_as_float(u << 16); }
__device__ __forceinline__ float bfhi(unsigned u) { return __uint_as_float(u & 0xffff0000u); }
__device__ __forceinline__ unsigned packbf2(float a, float b) {
  unsigned lo = (unsigned)__bfloat16_as_ushort(__float2bfloat16(a));
  unsigned hi = (unsigned)__bfloat16_as_ushort(__float2bfloat16(b));
  return lo | (hi << 16);
}
__device__ __forceinline__ float to_f(float v) { return v; }
__device__ __forceinline__ float to_f(bf16 v) { return __bfloat162float(v); }

// ---------------- dtype detector ----------------
// flag=1: float data is bf16; flag=0: float data is fp32.
// forced >= 0 overrides (host knows dtype in bytes-mode).
__global__ __launch_bounds__(256) void k_detect(const unsigned* __restrict__ x, int* __restrict__ flag,
                                                int forced) {
  __shared__ int sm[256];
  int t = threadIdx.x;
  if (forced >= 0) { if (t == 0) *flag = forced; return; }
  int cnt = 0;
  for (int i = t; i < 4096; i += 256) {
    unsigned u = x[i];
    unsigned lo_exp = (u >> 7) & 0xFF;   // exponent field of low bf16 (if bf16 pair)
    cnt += (lo_exp >= 97 && lo_exp <= 130) ? 1 : 0;
  }
  sm[t] = cnt;
  __syncthreads();
  for (int off = 128; off > 0; off >>= 1) {
    if (t < off) sm[t] += sm[t + off];
    __syncthreads();
  }
  if (t == 0) *flag = (sm[0] > 2048) ? 1 : 0;
}

// ---------------- graph preprocessing (dtype-independent) ----------------

__global__ __launch_bounds__(256) void k_init(int* deg, int* fil, int n) {
  int i = blockIdx.x * 256 + threadIdx.x;
  if (i < n) { deg[i] = 0; fil[i] = 0; }
}

__global__ __launch_bounds__(256) void k_deg(const int* __restrict__ dst, int* __restrict__ deg,
                                             int E, int N) {
  int e = blockIdx.x * 256 + threadIdx.x;
  if (e >= E) return;
  int d = dst[e];
  if ((unsigned)d < (unsigned)N) atomicAdd(&deg[d], 1);
}

__global__ __launch_bounds__(256) void k_dinv(const int* __restrict__ deg, float* __restrict__ dinv, int n) {
  int i = blockIdx.x * 256 + threadIdx.x;
  if (i < n) dinv[i] = rsqrtf((float)deg[i] + 1.0f);  // +1 self loop
}

// block handles 1024 elements (4/thread): block sums
__global__ __launch_bounds__(256) void k_scan1(const int* __restrict__ deg, int* __restrict__ bsum, int n) {
  __shared__ int ws[4];
  int t = threadIdx.x;
  int base = blockIdx.x * 1024 + t * 4;
  int s = 0;
#pragma unroll
  for (int j = 0; j < 4; ++j) { int i = base + j; if (i < n) s += deg[i]; }
#pragma unroll
  for (int off = 32; off > 0; off >>= 1) s += __shfl_down(s, off);
  if ((t & 63) == 0) ws[t >> 6] = s;
  __syncthreads();
  if (t == 0) bsum[blockIdx.x] = ws[0] + ws[1] + ws[2] + ws[3];
}

// single block, 256 threads: exclusive scan of block sums (NB <= 256)
__global__ __launch_bounds__(256) void k_scan2(const int* __restrict__ bsum, int* __restrict__ boff, int nb) {
  __shared__ int sm[256];
  int t = threadIdx.x;
  int v = (t < nb) ? bsum[t] : 0;
  sm[t] = v;
  __syncthreads();
  for (int off = 1; off < 256; off <<= 1) {
    int u = (t >= off) ? sm[t - off] : 0;
    __syncthreads();
    sm[t] += u;
    __syncthreads();
  }
  if (t < nb) boff[t] = sm[t] - v;  // exclusive
}

// full exclusive scan -> rowptr
__global__ __launch_bounds__(256) void k_scan3(const int* __restrict__ deg, const int* __restrict__ boff,
                                               int* __restrict__ rowptr, int n, int Etot) {
  __shared__ int sm[256];
  int t = threadIdx.x;
  int base = blockIdx.x * 1024 + t * 4;
  int v[4]; int s = 0;
#pragma unroll
  for (int j = 0; j < 4; ++j) { int i = base + j; v[j] = (i < n) ? deg[i] : 0; s += v[j]; }
  sm[t] = s;
  __syncthreads();
  for (int off = 1; off < 256; off <<= 1) {
    int u = (t >= off) ? sm[t - off] : 0;
    __syncthreads();
    sm[t] += u;
    __syncthreads();
  }
  int run = sm[t] - s + boff[blockIdx.x];
#pragma unroll
  for (int j = 0; j < 4; ++j) {
    int i = base + j;
    if (i < n) rowptr[i] = run;
    run += v[j];
  }
  if (blockIdx.x == 0 && t == 0) rowptr[n] = Etot;
}

__global__ __launch_bounds__(256) void k_fill(const int* __restrict__ src, const int* __restrict__ dst,
                                              const int* __restrict__ rowptr, int* __restrict__ fil,
                                              int* __restrict__ csr, int E, int N) {
  int e = blockIdx.x * 256 + threadIdx.x;
  if (e >= E) return;
  int d = dst[e];
  if ((unsigned)d >= (unsigned)N) return;
  int p = rowptr[d] + atomicAdd(&fil[d], 1);
  if ((unsigned)p >= (unsigned)E) return;  // clamp: never scatter OOB
  int s = src[e];
  csr[p] = ((unsigned)s < (unsigned)N) ? s : 0;
}

// ---------------- GEMM: C(bf16) = (A@B) * dinv[row] ----------------
// tile 64 rows x 128 cols, 256 threads, thread tile 4x8.

template <typename TA, typename TB, int WANT>
__global__ __launch_bounds__(256) void k_gemm128(const int* __restrict__ flag,
                                                 const TA* __restrict__ A, const TB* __restrict__ B,
                                                 const float* __restrict__ dinv, bf16* __restrict__ C,
                                                 int M, int K) {
  if (*flag != WANT) return;
  __shared__ float As[32][68];
  __shared__ float Bs[32][128];
  const int tid = threadIdx.x;
  const int row0 = blockIdx.x * 64;
  const int colg = tid & 15;
  const int rowg = tid >> 4;
  float acc[4][8];
#pragma unroll
  for (int i = 0; i < 4; ++i)
#pragma unroll
    for (int j = 0; j < 8; ++j) acc[i][j] = 0.f;

  for (int k0 = 0; k0 < K; k0 += 32) {
#pragma unroll
    for (int l = tid; l < 64 * 32; l += 256) {
      int r = l >> 5, kk = l & 31;
      int gr = row0 + r;
      As[kk][r] = (gr < M) ? to_f(A[(size_t)gr * K + k0 + kk]) : 0.f;
    }
#pragma unroll
    for (int l = tid; l < 32 * 128; l += 256) {
      int kk = l >> 7, c = l & 127;
      Bs[kk][c] = to_f(B[(size_t)(k0 + kk) * 128 + c]);
    }
    __syncthreads();
#pragma unroll
    for (int kk = 0; kk < 32; ++kk) {
      const float4 a  = *(const float4*)&As[kk][rowg * 4];
      const float4 b0 = *(const float4*)&Bs[kk][colg * 4];
      const float4 b1 = *(const float4*)&Bs[kk][64 + colg * 4];
      float av[4] = {a.x, a.y, a.z, a.w};
      float bv[8] = {b0.x, b0.y, b0.z, b0.w, b1.x, b1.y, b1.z, b1.w};
#pragma unroll
      for (int i = 0; i < 4; ++i)
#pragma unroll
        for (int j = 0; j < 8; ++j) acc[i][j] = fmaf(av[i], bv[j], acc[i][j]);
    }
    __syncthreads();
  }
#pragma unroll
  for (int i = 0; i < 4; ++i) {
    int r = row0 + rowg * 4 + i;
    if (r < M) {
      float s = dinv[r];
      uint2 o0, o1;
      o0.x = packbf2(acc[i][0] * s, acc[i][1] * s);
      o0.y = packbf2(acc[i][2] * s, acc[i][3] * s);
      o1.x = packbf2(acc[i][4] * s, acc[i][5] * s);
      o1.y = packbf2(acc[i][6] * s, acc[i][7] * s);
      *(uint2*)&C[(size_t)r * 128 + colg * 4] = o0;
      *(uint2*)&C[(size_t)r * 128 + 64 + colg * 4] = o1;
    }
  }
}

// F = 16, K = 128. A is always bf16 (ws intermediate). C fp32.
template <typename TB, int WANT>
__global__ __launch_bounds__(256) void k_gemm16(const int* __restrict__ flag,
                                                const bf16* __restrict__ A, const TB* __restrict__ B,
                                                const float* __restrict__ dinv, float* __restrict__ C, int M) {
  if (*flag != WANT) return;
  __shared__ float Bs[128][16];
  const int tid = threadIdx.x;
  for (int l = tid; l < 128 * 16; l += 256) Bs[l >> 4][l & 15] = to_f(B[l]);
  __syncthreads();
  const int r = blockIdx.x * 64 + (tid >> 2);
  const int c0 = (tid & 3) * 4;
  if (r >= M) return;
  const bf16* Ar = A + (size_t)r * 128;
  float a0 = 0.f, a1 = 0.f, a2 = 0.f, a3 = 0.f;
#pragma unroll
  for (int k = 0; k < 128; k += 8) {
    uint4 u = *(const uint4*)&Ar[k];
    float f[8] = {bflo(u.x), bfhi(u.x), bflo(u.y), bfhi(u.y),
                  bflo(u.z), bfhi(u.z), bflo(u.w), bfhi(u.w)};
#pragma unroll
    for (int j = 0; j < 8; ++j) {
      float4 b = *(const float4*)&Bs[k + j][c0];
      a0 = fmaf(f[j], b.x, a0); a1 = fmaf(f[j], b.y, a1);
      a2 = fmaf(f[j], b.z, a2); a3 = fmaf(f[j], b.w, a3);
    }
  }
  float s = dinv[r];
  *(float4*)&C[(size_t)r * 16 + c0] = make_float4(a0 * s, a1 * s, a2 * s, a3 * s);
}

// ---------------- aggregation (CSR gather) ----------------

// F=128: one wave per node, 2 bf16 cols per lane. out(bf16) = relu(sum*dinv + b)
template <typename TB, int WANT>
__global__ __launch_bounds__(256) void k_agg128(const int* __restrict__ flag,
                                                const bf16* __restrict__ Hs, const int* __restrict__ rowptr,
                                                const int* __restrict__ csr, const float* __restrict__ dinv,
                                                const TB* __restrict__ bias, bf16* __restrict__ out,
                                                int M, int Etot) {
  if (*flag != WANT) return;
  int wid = threadIdx.x >> 6, lane = threadIdx.x & 63;
  int node = blockIdx.x * 4 + wid;
  if (node >= M) return;
  int c = lane * 2;
  unsigned u = *(const unsigned*)&Hs[(size_t)node * 128 + c];  // self loop
  float ax = bflo(u), ay = bfhi(u);
  int e = rowptr[node], end = rowptr[node + 1];
  if (e < 0) e = 0;
  if (end > Etot) end = Etot;
  for (; e + 4 <= end; e += 4) {
    int s0 = csr[e], s1 = csr[e + 1], s2 = csr[e + 2], s3 = csr[e + 3];
    unsigned u0 = *(const unsigned*)&Hs[(size_t)s0 * 128 + c];
    unsigned u1 = *(const unsigned*)&Hs[(size_t)s1 * 128 + c];
    unsigned u2 = *(const unsigned*)&Hs[(size_t)s2 * 128 + c];
    unsigned u3 = *(const unsigned*)&Hs[(size_t)s3 * 128 + c];
    ax += bflo(u0) + bflo(u1) + bflo(u2) + bflo(u3);
    ay += bfhi(u0) + bfhi(u1) + bfhi(u2) + bfhi(u3);
  }
  for (; e < end; ++e) {
    unsigned uu = *(const unsigned*)&Hs[(size_t)csr[e] * 128 + c];
    ax += bflo(uu); ay += bfhi(uu);
  }
  float di = dinv[node];
  float ox = fmaxf(ax * di + to_f(bias[c]), 0.f);
  float oy = fmaxf(ay * di + to_f(bias[c + 1]), 0.f);
  *(unsigned*)&out[(size_t)node * 128 + c] = packbf2(ox, oy);
}

// F=16: 16 lanes per node, fp32 Hs in, output dtype TO (final layer, no relu)
template <typename TB, typename TO, int WANT>
__global__ __launch_bounds__(256) void k_agg16(const int* __restrict__ flag,
                                               const float* __restrict__ Hs, const int* __restrict__ rowptr,
                                               const int* __restrict__ csr, const float* __restrict__ dinv,
                                               const TB* __restrict__ bias, TO* __restrict__ out,
                                               int M, int Etot) {
  if (*flag != WANT) return;
  int sub = threadIdx.x >> 4, lane = threadIdx.x & 15;
  int node = blockIdx.x * 16 + sub;
  if (node >= M) return;
  float acc = Hs[(size_t)node * 16 + lane];  // self loop
  int e = rowptr[node], end = rowptr[node + 1];
  if (e < 0) e = 0;
  if (end > Etot) end = Etot;
  for (; e + 4 <= end; e += 4) {
    int s0 = csr[e], s1 = csr[e + 1], s2 = csr[e + 2], s3 = csr[e + 3];
    acc += Hs[(size_t)s0 * 16 + lane] + Hs[(size_t)s1 * 16 + lane] +
           Hs[(size_t)s2 * 16 + lane] + Hs[(size_t)s3 * 16 + lane];
  }
  for (; e < end; ++e) acc += Hs[(size_t)csr[e] * 16 + lane];
  float o = acc * dinv[node] + to_f(bias[lane]);
  out[(size_t)node * 16 + lane] = (TO)o;
}

// ---------------- launch ----------------

extern "C" void kernel_launch(void* const* d_in, const int* in_sizes, int n_in,
                              void* d_out, int out_size, void* d_ws, size_t ws_size,
                              hipStream_t stream) {
  const int* ei = (const int*)d_in[1];

  // Unit/dtype mode: W1 has 256*128 = 32768 elements.
  //   k=1: in_sizes in elements (dtype unknown -> device detector)
  //   k=2: in_sizes in bytes, floats are bf16
  //   k=4: in_sizes in bytes, floats are fp32
  const long long w1sz = in_sizes[2];
  const int kmode = (int)(w1sz / 32768);
  const int N = (int)((long long)in_sizes[0] * 128 / w1sz);
  const int E = (kmode == 1) ? in_sizes[1] / 2 : in_sizes[1] / 8;
  const int forced = (kmode == 2) ? 1 : (kmode == 4) ? 0 : -1;
  const int* srcv = ei;
  const int* dstv = ei + E;

  char* p = (char*)d_ws;
  auto alloc = [&](size_t b) { char* r = p; p += (b + 255) & ~(size_t)255; return r; };
  int*   flag   = (int*)alloc(256);
  int*   deg    = (int*)alloc((size_t)N * 4);
  int*   fil    = (int*)alloc((size_t)N * 4);
  int*   rowptr = (int*)alloc((size_t)(N + 1) * 4);
  float* dinv   = (float*)alloc((size_t)N * 4);
  const int NB = (N + 1023) / 1024;
  int*   bsum   = (int*)alloc((size_t)NB * 4);
  int*   boff   = (int*)alloc((size_t)NB * 4);
  int*   csr    = (int*)alloc((size_t)E * 4);
  bf16*  HsB    = (bf16*)alloc((size_t)N * 128 * 2);
  bf16*  hB     = (bf16*)alloc((size_t)N * 128 * 2);
  float* Hs16   = (float*)HsB;   // layer-3 gemm out: N*16 fp32 fits in N*128 bf16

  const int gN = (N + 255) / 256, gE = (E + 255) / 256;
  k_detect<<<1, 256, 0, stream>>>((const unsigned*)d_in[0], flag, forced);
  k_init <<<gN, 256, 0, stream>>>(deg, fil, N);
  k_deg  <<<gE, 256, 0, stream>>>(dstv, deg, E, N);
  k_dinv <<<gN, 256, 0, stream>>>(deg, dinv, N);
  k_scan1<<<NB, 256, 0, stream>>>(deg, bsum, N);
  k_scan2<<<1, 256, 0, stream>>>(bsum, boff, NB);
  k_scan3<<<NB, 256, 0, stream>>>(deg, boff, rowptr, N, E);
  k_fill <<<gE, 256, 0, stream>>>(srcv, dstv, rowptr, fil, csr, E, N);

  const int gM64 = (N + 63) / 64;
  const int gAgg = (N + 3) / 4;

  // bf16-input variants (flag==1)
  {
    const bf16* x  = (const bf16*)d_in[0];
    const bf16* W1 = (const bf16*)d_in[2]; const bf16* b1 = (const bf16*)d_in[3];
    const bf16* W2 = (const bf16*)d_in[4]; const bf16* b2 = (const bf16*)d_in[5];
    const bf16* W3 = (const bf16*)d_in[6]; const bf16* b3 = (const bf16*)d_in[7];
    k_gemm128<bf16, bf16, 1><<<gM64, 256, 0, stream>>>(flag, x, W1, dinv, HsB, N, 256);
    k_agg128<bf16, 1><<<gAgg, 256, 0, stream>>>(flag, HsB, rowptr, csr, dinv, b1, hB, N, E);
    k_gemm128<bf16, bf16, 1><<<gM64, 256, 0, stream>>>(flag, hB, W2, dinv, HsB, N, 128);
    k_agg128<bf16, 1><<<gAgg, 256, 0, stream>>>(flag, HsB, rowptr, csr, dinv, b2, hB, N, E);
    k_gemm16<bf16, 1><<<gM64, 256, 0, stream>>>(flag, hB, W3, dinv, Hs16, N);
    k_agg16<bf16, bf16, 1><<<(N + 15) / 16, 256, 0, stream>>>(flag, Hs16, rowptr, csr, dinv, b3,
                                                              (bf16*)d_out, N, E);
  }
  // fp32-input variants (flag==0)
  {
    const float* x  = (const float*)d_in[0];
    const float* W1 = (const float*)d_in[2]; const float* b1 = (const float*)d_in[3];
    const float* W2 = (const float*)d_in[4]; const float* b2 = (const float*)d_in[5];
    const float* W3 = (const float*)d_in[6]; const float* b3 = (const float*)d_in[7];
    k_gemm128<float, float, 0><<<gM64, 256, 0, stream>>>(flag, x, W1, dinv, HsB, N, 256);
    k_agg128<float, 0><<<gAgg, 256, 0, stream>>>(flag, HsB, rowptr, csr, dinv, b1, hB, N, E);
    k_gemm128<bf16, float, 0><<<gM64, 256, 0, stream>>>(flag, hB, W2, dinv, HsB, N, 128);
    k_agg128<float, 0><<<gAgg, 256, 0, stream>>>(flag, HsB, rowptr, csr, dinv, b2, hB, N, E);
    k_gemm16<float, 0><<<gM64, 256, 0, stream>>>(flag, hB, W3, dinv, Hs16, N);
    k_agg16<float, float, 0><<<(N + 15) / 16, 256, 0, stream>>>(flag, Hs16, rowptr, csr, dinv, b3,
                                                                (float*)d_out, N, E);
  }
}